// Round 13
// baseline (786.906 us; speedup 1.0000x reference)
//
#include <hip/hip_runtime.h>
#include <cstddef>
#include <cstdint>

typedef __attribute__((ext_vector_type(4))) float f32x4;
typedef __attribute__((ext_vector_type(8))) short short8;

#define HID 128
#define NK1 -1.4426950408889634f  // -log2(e)
#define PK2 2.8853900817779268f   // +2*log2(e)

// LDS-only barrier: no vmcnt(0) drain.
#define BAR_LGKM() __asm__ volatile("s_waitcnt lgkmcnt(0)\ns_barrier" ::: "memory")
// depth-2 prefetch fence: retire gather(t), keep gather(t+1) in flight
#define STEP_BAR2() __asm__ volatile("s_waitcnt vmcnt(2) lgkmcnt(0)\ns_barrier" ::: "memory")

__device__ __forceinline__ short f2bf(float f) {
  unsigned u = __builtin_bit_cast(unsigned, f);
  u += 0x7FFFu + ((u >> 16) & 1u);
  return (short)(u >> 16);
}
__device__ __forceinline__ unsigned pack_bf2(float a, float b) {
  unsigned ua = __builtin_bit_cast(unsigned, a) + 0x8000u;
  unsigned ub = __builtin_bit_cast(unsigned, b) + 0x8000u;
  return __builtin_amdgcn_perm(ub, ua, 0x07060302u);
}
__device__ __forceinline__ float2 unpack2v(int w) {
  float2 r;
  r.x = __builtin_bit_cast(float, (unsigned)(w << 16));
  r.y = __builtin_bit_cast(float, (unsigned)w & 0xffff0000u);
  return r;
}

// folded LSTM cell: inputs are PRE-SCALED pre-activations
// si,sf,so = -log2e*(gate), sg = 2log2e*(g). 5 exp2 + 2 rcp (algebraic min).
__device__ __forceinline__ float lstm_elem(float si, float sf, float sg, float so, float& c) {
  float Ei = __builtin_amdgcn_exp2f(si);
  float Ef = __builtin_amdgcn_exp2f(sf);
  float Tg = __builtin_amdgcn_exp2f(sg);
  float Eo = __builtin_amdgcn_exp2f(so);
  float u = 1.0f + Ei, w = 1.0f + Ef, v = Tg + 1.0f, Tm = Tg - 1.0f;
  float t0 = u * v;
  float num = __builtin_fmaf(c, t0, w * Tm);
  float cn = num * __builtin_amdgcn_rcpf(w * t0);
  c = cn;
  float Tc = __builtin_amdgcn_exp2f(PK2 * cn);
  return (Tc - 1.0f) * __builtin_amdgcn_rcpf((1.0f + Eo) * (Tc + 1.0f));
}

// ---------------- conversion kernels ----------------
__global__ void conv_x_kernel(const float* __restrict__ x, short* __restrict__ xb, int n) {
  int i = blockIdx.x * blockDim.x + threadIdx.x;
  int stride = gridDim.x * blockDim.x;
  for (; i < n; i += stride) xb[i] = f2bf(x[i]);
}

// pre-scales LSTM weights/bias by gate: i,f,o -> -log2e ; g -> +2log2e
__global__ void conv_layer_kernel(const float* __restrict__ Wih, const float* __restrict__ Whh,
                                  const float* __restrict__ bih, const float* __restrict__ bhh,
                                  const float* __restrict__ Wl, const float* __restrict__ Wr, int foK,
                                  short* __restrict__ wihB, short* __restrict__ whhB,
                                  short* __restrict__ wlB, short* __restrict__ wrB,
                                  float* __restrict__ bsum) {
  int i = blockIdx.x * blockDim.x + threadIdx.x;
  if (i < 512 * HID) {
    float sc = ((i >> 14) == 2) ? PK2 : NK1;  // gate = row>>7 = i>>14
    wihB[i] = f2bf(Wih[i] * sc);
    whhB[i] = f2bf(Whh[i] * sc);
  }
  if (i < foK) { wlB[i] = f2bf(Wl[i]); wrB[i] = f2bf(Wr[i]); }
  if (i < 512) bsum[i] = (bih[i] + bhh[i]) * (((i >> 7) == 2) ? PK2 : NK1);
}

// ------- persistent P-GEMM: P = A @ Wih^T + bias -> bf16 [M,512] -------------
// DIRECT-STORE epilogue (no LDS bounce, no barriers): lane owns (node=nn+16b,
// pcols cbase+nt*16+quad*4..+4) -> uint2 stores; fixed nt = 16 rows x 32B
// contiguous, consecutive nt fill consecutive 32B sectors (L2 sector-merged).
// Same pattern as the r12 fused epilogue (proven fine).
__global__ __launch_bounds__(512, 4) void pgemm_kernel(
    const short* __restrict__ A, const short* __restrict__ W,
    const float* __restrict__ bias, short* __restrict__ out, int M, int ntiles) {
  const int tid = threadIdx.x;
  const int wave = tid >> 6, lane = tid & 63;
  const int quad = lane >> 4, nn = lane & 15;
  const int cbase = wave * 64;

  short8 wreg[4][4];
#pragma unroll
  for (int kt = 0; kt < 4; ++kt)
#pragma unroll
    for (int nt = 0; nt < 4; ++nt)
      wreg[kt][nt] = *(const short8*)(W + (size_t)(cbase + nt * 16 + nn) * HID + kt * 32 + quad * 8);
  f32x4 bias4[4];
#pragma unroll
  for (int nt = 0; nt < 4; ++nt)
#pragma unroll
    for (int r = 0; r < 4; ++r) bias4[nt][r] = bias[cbase + nt * 16 + quad * 4 + r];

#pragma unroll 1
  for (int rt = blockIdx.x; rt < ntiles; rt += gridDim.x) {
    const int row0 = rt * 32;
    f32x4 acc[2][4];
#pragma unroll
    for (int b = 0; b < 2; ++b)
#pragma unroll
      for (int nt = 0; nt < 4; ++nt) acc[b][nt] = bias4[nt];
#pragma unroll
    for (int kt = 0; kt < 4; ++kt) {
      int r0 = row0 + nn;      if (r0 > M - 1) r0 = M - 1;
      int r1 = row0 + 16 + nn; if (r1 > M - 1) r1 = M - 1;
      short8 af0 = *(const short8*)(A + (size_t)r0 * HID + kt * 32 + quad * 8);
      short8 af1 = *(const short8*)(A + (size_t)r1 * HID + kt * 32 + quad * 8);
#pragma unroll
      for (int nt = 0; nt < 4; ++nt) {
        acc[0][nt] = __builtin_amdgcn_mfma_f32_16x16x32_bf16(wreg[kt][nt], af0, acc[0][nt], 0, 0, 0);
        acc[1][nt] = __builtin_amdgcn_mfma_f32_16x16x32_bf16(wreg[kt][nt], af1, acc[1][nt], 0, 0, 0);
      }
    }
    // direct D-layout stores
#pragma unroll
    for (int b = 0; b < 2; ++b) {
      int node = row0 + b * 16 + nn;
      if (node < M) {
#pragma unroll
        for (int nt = 0; nt < 4; ++nt) {
          uint2 pk;
          pk.x = pack_bf2(acc[b][nt][0], acc[b][nt][1]);
          pk.y = pack_bf2(acc[b][nt][2], acc[b][nt][3]);
          *(uint2*)(out + (size_t)node * 512 + cbase + nt * 16 + quad * 4) = pk;
        }
      }
    }
  }
}

// ------- persistent LSTM + FUSED output GEMM (r12 structure, unchanged) -----
#define NPB 16
#define PSTR 520
#define HSTR 152
#define LSTM_LDS_BYTES ((3 * NPB * PSTR + 2 * NPB * HSTR) * 2 + 256 * 4)  // 60672

template <int FO, bool RELU, bool OUTF32>
__global__ __launch_bounds__(512, 4) void lstm_fused_kernel(
    const short* __restrict__ P, const short* __restrict__ Whh,
    const int* __restrict__ src, const short* __restrict__ cur,
    const short* __restrict__ Wl, const short* __restrict__ Wr,
    const float* __restrict__ bl,
    short* __restrict__ outB, float* __restrict__ outF, int M, int ntiles) {
  extern __shared__ char smem[];
  short* Pb = (short*)smem;                 // [3][16][520]
  short* Hb = Pb + 3 * NPB * PSTR;          // [2][16][152]
  int* srcL = (int*)(Hb + 2 * NPB * HSTR);  // [256]

  const int tid = threadIdx.x;
  const int wave = tid >> 6, lane = tid & 63;
  const int quad = lane >> 4, nn = lane & 15;
  const int r0row = wave * 2, r1row = wave * 2 + 1;

  // Whh fragments: for each gate q, rows [q*128 + wave*16, +16)  (64 VGPRs)
  short8 wreg[4][4];  // [kt][q]
#pragma unroll
  for (int kt = 0; kt < 4; ++kt)
#pragma unroll
    for (int q = 0; q < 4; ++q)
      wreg[kt][q] = *(const short8*)(Whh + (size_t)(q * 128 + wave * 16 + nn) * HID + kt * 32 + quad * 8);

  // output bias for this wave's out-col chunk
  f32x4 biasO = {0.f, 0.f, 0.f, 0.f};
  if (FO == 128 || wave < 4) {
#pragma unroll
    for (int r = 0; r < 4; ++r) biasO[r] = bl[wave * 16 + quad * 4 + r];
  }

#pragma unroll 1
  for (int tile = blockIdx.x; tile < ntiles; tile += gridDim.x) {
    const int nodeBase = tile * NPB;
    if (tid < 256) {
      int node = nodeBase + (tid >> 4);
      srcL[tid] = (node < M) ? src[nodeBase * 16 + tid] : 0;
    }
    float c_st[4] = {0.f, 0.f, 0.f, 0.f};
    BAR_LGKM();  // srcL visible; prev tile's LDS reads done

    // prologue: gather(0) -> buf0, gather(1) -> buf1
    {
      int s0A = srcL[r0row * 16 + 0], s0B = srcL[r1row * 16 + 0];
      __builtin_amdgcn_global_load_lds(
          (const __attribute__((address_space(1))) unsigned int*)(P + (size_t)s0A * 512 + lane * 8),
          (__attribute__((address_space(3))) unsigned int*)(Pb + r0row * PSTR), 16, 0, 0);
      __builtin_amdgcn_global_load_lds(
          (const __attribute__((address_space(1))) unsigned int*)(P + (size_t)s0B * 512 + lane * 8),
          (__attribute__((address_space(3))) unsigned int*)(Pb + r1row * PSTR), 16, 0, 0);
      int s1A = srcL[r0row * 16 + 1], s1B = srcL[r1row * 16 + 1];
      __builtin_amdgcn_global_load_lds(
          (const __attribute__((address_space(1))) unsigned int*)(P + (size_t)s1A * 512 + lane * 8),
          (__attribute__((address_space(3))) unsigned int*)(Pb + NPB * PSTR + r0row * PSTR), 16, 0, 0);
      __builtin_amdgcn_global_load_lds(
          (const __attribute__((address_space(1))) unsigned int*)(P + (size_t)s1B * 512 + lane * 8),
          (__attribute__((address_space(3))) unsigned int*)(Pb + NPB * PSTR + r1row * PSTR), 16, 0, 0);
    }
    int sA = srcL[r0row * 16 + 2], sB = srcL[r1row * 16 + 2];

    int pc = 0, pg = 2;  // buffer index of P(t) and of gather target (t+2)
#pragma unroll 1
    for (int t = 0; t < 16; ++t) {
      short* Pc = Pb + pc * NPB * PSTR;
      short* Pg = Pb + pg * NPB * PSTR;
      const short* Hp = Hb + ((t + 1) & 1) * NPB * HSTR;  // h(t-1)
      short* Hw = Hb + (t & 1) * NPB * HSTR;              // h(t)
      pc = (pc == 2) ? 0 : pc + 1;
      pg = (pg == 2) ? 0 : pg + 1;

      STEP_BAR2();  // gather(t) landed everywhere; gather(t+1) stays in flight

      // ---- read P-frags and unpack INTO acc (MFMA C-operand) ----
      const short* pR = Pc + nn * PSTR + wave * 16 + quad * 4;
      uint2 p0 = *(const uint2*)(pR + 0 * 128);
      uint2 p1 = *(const uint2*)(pR + 1 * 128);
      uint2 p2 = *(const uint2*)(pR + 2 * 128);
      uint2 p3 = *(const uint2*)(pR + 3 * 128);
      f32x4 acc[4];
      {
        float2 u, v;
        u = unpack2v(p0.x); v = unpack2v(p0.y);
        acc[0][0] = u.x; acc[0][1] = u.y; acc[0][2] = v.x; acc[0][3] = v.y;
        u = unpack2v(p1.x); v = unpack2v(p1.y);
        acc[1][0] = u.x; acc[1][1] = u.y; acc[1][2] = v.x; acc[1][3] = v.y;
        u = unpack2v(p2.x); v = unpack2v(p2.y);
        acc[2][0] = u.x; acc[2][1] = u.y; acc[2][2] = v.x; acc[2][3] = v.y;
        u = unpack2v(p3.x); v = unpack2v(p3.y);
        acc[3][0] = u.x; acc[3][1] = u.y; acc[3][2] = v.x; acc[3][3] = v.y;
      }

      // ---- issue gather(t+2) (clamped dummy at t>=14 keeps vmcnt uniform) ----
      __builtin_amdgcn_global_load_lds(
          (const __attribute__((address_space(1))) unsigned int*)(P + (size_t)sA * 512 + lane * 8),
          (__attribute__((address_space(3))) unsigned int*)(Pg + r0row * PSTR), 16, 0, 0);
      __builtin_amdgcn_global_load_lds(
          (const __attribute__((address_space(1))) unsigned int*)(P + (size_t)sB * 512 + lane * 8),
          (__attribute__((address_space(3))) unsigned int*)(Pg + r1row * PSTR), 16, 0, 0);
      {
        int tn = (t + 3 < 16) ? t + 3 : 15;
        sA = srcL[r0row * 16 + tn];
        sB = srcL[r1row * 16 + tn];
      }

      // ---- acc += Whh_rows @ h(t-1)^T ----
      if (t) {
#pragma unroll
        for (int kt = 0; kt < 4; ++kt) {
          short8 hb = *(const short8*)(Hp + nn * HSTR + kt * 32 + quad * 8);
#pragma unroll
          for (int q = 0; q < 4; ++q)
            acc[q] = __builtin_amdgcn_mfma_f32_16x16x32_bf16(wreg[kt][q], hb, acc[q], 0, 0, 0);
        }
      }

      // ---- cell: pure register math, write h(t) ----
      float hv[4];
#pragma unroll
      for (int r = 0; r < 4; ++r)
        hv[r] = lstm_elem(acc[0][r], acc[1][r], acc[2][r], acc[3][r], c_st[r]);
      uint2 pk;
      pk.x = pack_bf2(hv[0], hv[1]);
      pk.y = pack_bf2(hv[2], hv[3]);
      *(uint2*)(Hw + nn * HSTR + wave * 16 + quad * 4) = pk;
    }

    BAR_LGKM();  // h(15) visible (buf1)

    // ---- FUSED output: out[node] = h15@Wl^T + bl + cur@Wr^T ----
    if (FO == 128 || wave < 4) {
      const short* Hf = Hb + NPB * HSTR;
      const int cbase = wave * 16;
      f32x4 accO = biasO;
#pragma unroll
      for (int kt = 0; kt < 4; ++kt) {
        short8 wlA = *(const short8*)(Wl + (size_t)(cbase + nn) * HID + kt * 32 + quad * 8);
        short8 hb = *(const short8*)(Hf + nn * HSTR + kt * 32 + quad * 8);
        accO = __builtin_amdgcn_mfma_f32_16x16x32_bf16(wlA, hb, accO, 0, 0, 0);
        short8 wrA = *(const short8*)(Wr + (size_t)(cbase + nn) * HID + kt * 32 + quad * 8);
        short8 cb = *(const short8*)(cur + (size_t)(nodeBase + nn) * HID + kt * 32 + quad * 8);
        accO = __builtin_amdgcn_mfma_f32_16x16x32_bf16(wrA, cb, accO, 0, 0, 0);
      }
      if (RELU) {
#pragma unroll
        for (int r = 0; r < 4; ++r) accO[r] = fmaxf(accO[r], 0.0f);
      }
      int node = nodeBase + nn;
      if (node < M) {
        if (OUTF32) {
          *(f32x4*)(outF + (size_t)node * FO + cbase + quad * 4) = accO;
        } else {
          uint2 pko;
          pko.x = pack_bf2(accO[0], accO[1]);
          pko.y = pack_bf2(accO[2], accO[3]);
          *(uint2*)(outB + (size_t)node * FO + cbase + quad * 4) = pko;
        }
      }
    }
  }
}

// ---------------- launcher ----------------
extern "C" void kernel_launch(void* const* d_in, const int* in_sizes, int n_in,
                              void* d_out, int out_size, void* d_ws, size_t ws_size,
                              hipStream_t stream) {
  const float* x = (const float*)d_in[0];
  const int* src = (const int*)d_in[1];
  const float* Wih[3] = {(const float*)d_in[2], (const float*)d_in[9], (const float*)d_in[16]};
  const float* Whh[3] = {(const float*)d_in[3], (const float*)d_in[10], (const float*)d_in[17]};
  const float* bih[3] = {(const float*)d_in[4], (const float*)d_in[11], (const float*)d_in[18]};
  const float* bhh[3] = {(const float*)d_in[5], (const float*)d_in[12], (const float*)d_in[19]};
  const float* Wl[3]  = {(const float*)d_in[6], (const float*)d_in[13], (const float*)d_in[20]};
  const float* bl[3]  = {(const float*)d_in[7], (const float*)d_in[14], (const float*)d_in[21]};
  const float* Wr[3]  = {(const float*)d_in[8], (const float*)d_in[15], (const float*)d_in[22]};

  const int M = in_sizes[0] / HID;  // 50000

  char* ws = (char*)d_ws;
  size_t off = 0;
  auto alloc = [&](size_t bytes) -> void* {
    void* p = ws + off;
    off += (bytes + 255) & ~(size_t)255;
    return p;
  };
  short* curA = (short*)alloc((size_t)M * HID * 2);
  short* curB = (short*)alloc((size_t)M * HID * 2);
  short* Pbuf = (short*)alloc((size_t)M * 512 * 2);
  short* wihB[3]; short* whhB[3]; short* wlB[3]; short* wrB[3]; float* bsum[3];
  for (int l = 0; l < 3; ++l) {
    wihB[l] = (short*)alloc(512 * HID * 2);
    whhB[l] = (short*)alloc(512 * HID * 2);
    wlB[l]  = (short*)alloc(HID * HID * 2);
    wrB[l]  = (short*)alloc(HID * HID * 2);
    bsum[l] = (float*)alloc(512 * 4);
  }

  const int nltiles = (M + NPB - 1) / NPB;  // 3125
  const int ntiles = (M + 31) / 32;         // 1563

  (void)hipFuncSetAttribute((const void*)lstm_fused_kernel<128, true, false>,
                            hipFuncAttributeMaxDynamicSharedMemorySize, LSTM_LDS_BYTES);
  (void)hipFuncSetAttribute((const void*)lstm_fused_kernel<64, false, true>,
                            hipFuncAttributeMaxDynamicSharedMemorySize, LSTM_LDS_BYTES);

  conv_x_kernel<<<2048, 256, 0, stream>>>(x, curA, M * HID);
  for (int l = 0; l < 3; ++l) {
    const int Fo = (l == 2) ? 64 : 128;
    conv_layer_kernel<<<256, 256, 0, stream>>>(Wih[l], Whh[l], bih[l], bhh[l], Wl[l], Wr[l],
                                               Fo * HID, wihB[l], whhB[l], wlB[l], wrB[l], bsum[l]);
  }

  short* cur = curA;
  short* nxt = curB;
  for (int l = 0; l < 3; ++l) {
    pgemm_kernel<<<784, 512, 0, stream>>>(cur, wihB[l], bsum[l], Pbuf, M, ntiles);
    if (l < 2) {
      lstm_fused_kernel<128, true, false><<<512, 512, LSTM_LDS_BYTES, stream>>>(
          Pbuf, whhB[l], src, cur, wlB[l], wrB[l], bl[l], nxt, nullptr, M, nltiles);
      short* tswap = cur; cur = nxt; nxt = tswap;
    } else {
      lstm_fused_kernel<64, false, true><<<512, 512, LSTM_LDS_BYTES, stream>>>(
          Pbuf, whhB[l], src, cur, wlB[l], wrB[l], bl[l], nullptr, (float*)d_out, M, nltiles);
    }
  }
}

// Round 14
// 783.116 us; speedup vs baseline: 1.0048x; 1.0048x over previous
//
#include <hip/hip_runtime.h>
#include <cstddef>
#include <cstdint>

typedef __attribute__((ext_vector_type(4))) float f32x4;
typedef __attribute__((ext_vector_type(8))) short short8;

#define HID 128
#define NK1 -1.4426950408889634f  // -log2(e)
#define PK2 2.8853900817779268f   // +2*log2(e)

// LDS-only barrier: no vmcnt(0) drain.
#define BAR_LGKM() __asm__ volatile("s_waitcnt lgkmcnt(0)\ns_barrier" ::: "memory")
// depth-2 prefetch fence: retire gather(t), keep gather(t+1) in flight
#define STEP_BAR2() __asm__ volatile("s_waitcnt vmcnt(2) lgkmcnt(0)\ns_barrier" ::: "memory")

__device__ __forceinline__ short f2bf(float f) {
  unsigned u = __builtin_bit_cast(unsigned, f);
  u += 0x7FFFu + ((u >> 16) & 1u);
  return (short)(u >> 16);
}
// pack two f32 -> two bf16 (round-half-up) in one u32 via v_perm
__device__ __forceinline__ unsigned pack_bf2(float a, float b) {
  unsigned ua = __builtin_bit_cast(unsigned, a) + 0x8000u;
  unsigned ub = __builtin_bit_cast(unsigned, b) + 0x8000u;
  return __builtin_amdgcn_perm(ub, ua, 0x07060302u);
}
__device__ __forceinline__ float2 unpack2v(int w) {
  float2 r;
  r.x = __builtin_bit_cast(float, (unsigned)(w << 16));
  r.y = __builtin_bit_cast(float, (unsigned)w & 0xffff0000u);
  return r;
}
// load 8 consecutive f32 and pack to a bf16 MFMA fragment (short8)
__device__ __forceinline__ short8 f32frag(const float* p) {
  f32x4 a = *(const f32x4*)p;
  f32x4 b = *(const f32x4*)(p + 4);
  short8 r;
  int* ri = (int*)&r;
  ri[0] = (int)pack_bf2(a[0], a[1]);
  ri[1] = (int)pack_bf2(a[2], a[3]);
  ri[2] = (int)pack_bf2(b[0], b[1]);
  ri[3] = (int)pack_bf2(b[2], b[3]);
  return r;
}

// folded LSTM cell: inputs are PRE-SCALED pre-activations
// si,sf,so = -log2e*(gate), sg = 2log2e*(g). 5 exp2 + 2 rcp (algebraic min).
__device__ __forceinline__ float lstm_elem(float si, float sf, float sg, float so, float& c) {
  float Ei = __builtin_amdgcn_exp2f(si);
  float Ef = __builtin_amdgcn_exp2f(sf);
  float Tg = __builtin_amdgcn_exp2f(sg);
  float Eo = __builtin_amdgcn_exp2f(so);
  float u = 1.0f + Ei, w = 1.0f + Ef, v = Tg + 1.0f, Tm = Tg - 1.0f;
  float t0 = u * v;
  float num = __builtin_fmaf(c, t0, w * Tm);
  float cn = num * __builtin_amdgcn_rcpf(w * t0);
  c = cn;
  float Tc = __builtin_amdgcn_exp2f(PK2 * cn);
  return (Tc - 1.0f) * __builtin_amdgcn_rcpf((1.0f + Eo) * (Tc + 1.0f));
}

// pre-scales LSTM weights/bias by gate: i,f,o -> -log2e ; g -> +2log2e
__global__ void conv_layer_kernel(const float* __restrict__ Wih, const float* __restrict__ Whh,
                                  const float* __restrict__ bih, const float* __restrict__ bhh,
                                  const float* __restrict__ Wl, const float* __restrict__ Wr, int foK,
                                  short* __restrict__ wihB, short* __restrict__ whhB,
                                  short* __restrict__ wlB, short* __restrict__ wrB,
                                  float* __restrict__ bsum) {
  int i = blockIdx.x * blockDim.x + threadIdx.x;
  if (i < 512 * HID) {
    float sc = ((i >> 14) == 2) ? PK2 : NK1;  // gate = row>>7 = i>>14
    wihB[i] = f2bf(Wih[i] * sc);
    whhB[i] = f2bf(Whh[i] * sc);
  }
  if (i < foK) { wlB[i] = f2bf(Wl[i]); wrB[i] = f2bf(Wr[i]); }
  if (i < 512) bsum[i] = (bih[i] + bhh[i]) * (((i >> 7) == 2) ? PK2 : NK1);
}

// ------- persistent P-GEMM: P = A @ Wih^T + bias -> bf16 [M,512] -------------
// r12 LDS-bounce epilogue (proven best). INF32: A is f32 (layer 1, reads x
// directly -> conv_x pass deleted), packed to bf16 fragments in-register.
#define OSTR 524
template <bool INF32>
__global__ __launch_bounds__(512, 4) void pgemm_kernel(
    const void* __restrict__ A, const short* __restrict__ W,
    const float* __restrict__ bias, short* __restrict__ out, int M, int ntiles) {
  __shared__ short ldsO[32 * OSTR];  // 33.5 KB
  const int tid = threadIdx.x;
  const int wave = tid >> 6, lane = tid & 63;
  const int quad = lane >> 4, nn = lane & 15;
  const int cbase = wave * 64;

  short8 wreg[4][4];
#pragma unroll
  for (int kt = 0; kt < 4; ++kt)
#pragma unroll
    for (int nt = 0; nt < 4; ++nt)
      wreg[kt][nt] = *(const short8*)(W + (size_t)(cbase + nt * 16 + nn) * HID + kt * 32 + quad * 8);
  f32x4 bias4[4];
#pragma unroll
  for (int nt = 0; nt < 4; ++nt)
#pragma unroll
    for (int r = 0; r < 4; ++r) bias4[nt][r] = bias[cbase + nt * 16 + quad * 4 + r];

#pragma unroll 1
  for (int rt = blockIdx.x; rt < ntiles; rt += gridDim.x) {
    const int row0 = rt * 32;
    f32x4 acc[2][4];
#pragma unroll
    for (int b = 0; b < 2; ++b)
#pragma unroll
      for (int nt = 0; nt < 4; ++nt) acc[b][nt] = bias4[nt];
#pragma unroll
    for (int kt = 0; kt < 4; ++kt) {
      int r0 = row0 + nn;      if (r0 > M - 1) r0 = M - 1;
      int r1 = row0 + 16 + nn; if (r1 > M - 1) r1 = M - 1;
      short8 af0, af1;
      if (INF32) {
        af0 = f32frag((const float*)A + (size_t)r0 * HID + kt * 32 + quad * 8);
        af1 = f32frag((const float*)A + (size_t)r1 * HID + kt * 32 + quad * 8);
      } else {
        af0 = *(const short8*)((const short*)A + (size_t)r0 * HID + kt * 32 + quad * 8);
        af1 = *(const short8*)((const short*)A + (size_t)r1 * HID + kt * 32 + quad * 8);
      }
#pragma unroll
      for (int nt = 0; nt < 4; ++nt) {
        acc[0][nt] = __builtin_amdgcn_mfma_f32_16x16x32_bf16(wreg[kt][nt], af0, acc[0][nt], 0, 0, 0);
        acc[1][nt] = __builtin_amdgcn_mfma_f32_16x16x32_bf16(wreg[kt][nt], af1, acc[1][nt], 0, 0, 0);
      }
    }
    BAR_LGKM();  // previous iteration's ldsO reads complete
#pragma unroll
    for (int b = 0; b < 2; ++b)
#pragma unroll
      for (int nt = 0; nt < 4; ++nt) {
        uint2 pk;
        pk.x = pack_bf2(acc[b][nt][0], acc[b][nt][1]);
        pk.y = pack_bf2(acc[b][nt][2], acc[b][nt][3]);
        *(uint2*)(ldsO + (b * 16 + nn) * OSTR + cbase + nt * 16 + quad * 4) = pk;
      }
    BAR_LGKM();
#pragma unroll
    for (int idx = tid; idx < 32 * 64; idx += 512) {
      int row = idx >> 6, c8 = (idx & 63) * 8;
      if (row0 + row < M)
        *(short8*)(out + (size_t)(row0 + row) * 512 + c8) = *(const short8*)(ldsO + row * OSTR + c8);
    }
  }
}

// ------- persistent LSTM + FUSED output GEMM (r12 structure) ----------------
// CURF32: cur (the lin_r input) is f32 (layer 1 = x), packed in-register.
#define NPB 16
#define PSTR 520
#define HSTR 152
#define LSTM_LDS_BYTES ((3 * NPB * PSTR + 2 * NPB * HSTR) * 2 + 256 * 4)  // 60672

template <int FO, bool RELU, bool OUTF32, bool CURF32>
__global__ __launch_bounds__(512, 4) void lstm_fused_kernel(
    const short* __restrict__ P, const short* __restrict__ Whh,
    const int* __restrict__ src, const void* __restrict__ cur,
    const short* __restrict__ Wl, const short* __restrict__ Wr,
    const float* __restrict__ bl,
    short* __restrict__ outB, float* __restrict__ outF, int M, int ntiles) {
  extern __shared__ char smem[];
  short* Pb = (short*)smem;                 // [3][16][520]
  short* Hb = Pb + 3 * NPB * PSTR;          // [2][16][152]
  int* srcL = (int*)(Hb + 2 * NPB * HSTR);  // [256]

  const int tid = threadIdx.x;
  const int wave = tid >> 6, lane = tid & 63;
  const int quad = lane >> 4, nn = lane & 15;
  const int r0row = wave * 2, r1row = wave * 2 + 1;

  // Whh fragments: for each gate q, rows [q*128 + wave*16, +16)  (64 VGPRs)
  short8 wreg[4][4];  // [kt][q]
#pragma unroll
  for (int kt = 0; kt < 4; ++kt)
#pragma unroll
    for (int q = 0; q < 4; ++q)
      wreg[kt][q] = *(const short8*)(Whh + (size_t)(q * 128 + wave * 16 + nn) * HID + kt * 32 + quad * 8);

  // output bias for this wave's out-col chunk
  f32x4 biasO = {0.f, 0.f, 0.f, 0.f};
  if (FO == 128 || wave < 4) {
#pragma unroll
    for (int r = 0; r < 4; ++r) biasO[r] = bl[wave * 16 + quad * 4 + r];
  }

#pragma unroll 1
  for (int tile = blockIdx.x; tile < ntiles; tile += gridDim.x) {
    const int nodeBase = tile * NPB;
    if (tid < 256) {
      int node = nodeBase + (tid >> 4);
      srcL[tid] = (node < M) ? src[nodeBase * 16 + tid] : 0;
    }
    float c_st[4] = {0.f, 0.f, 0.f, 0.f};
    BAR_LGKM();  // srcL visible; prev tile's LDS reads done

    // prologue: gather(0) -> buf0, gather(1) -> buf1
    {
      int s0A = srcL[r0row * 16 + 0], s0B = srcL[r1row * 16 + 0];
      __builtin_amdgcn_global_load_lds(
          (const __attribute__((address_space(1))) unsigned int*)(P + (size_t)s0A * 512 + lane * 8),
          (__attribute__((address_space(3))) unsigned int*)(Pb + r0row * PSTR), 16, 0, 0);
      __builtin_amdgcn_global_load_lds(
          (const __attribute__((address_space(1))) unsigned int*)(P + (size_t)s0B * 512 + lane * 8),
          (__attribute__((address_space(3))) unsigned int*)(Pb + r1row * PSTR), 16, 0, 0);
      int s1A = srcL[r0row * 16 + 1], s1B = srcL[r1row * 16 + 1];
      __builtin_amdgcn_global_load_lds(
          (const __attribute__((address_space(1))) unsigned int*)(P + (size_t)s1A * 512 + lane * 8),
          (__attribute__((address_space(3))) unsigned int*)(Pb + NPB * PSTR + r0row * PSTR), 16, 0, 0);
      __builtin_amdgcn_global_load_lds(
          (const __attribute__((address_space(1))) unsigned int*)(P + (size_t)s1B * 512 + lane * 8),
          (__attribute__((address_space(3))) unsigned int*)(Pb + NPB * PSTR + r1row * PSTR), 16, 0, 0);
    }
    int sA = srcL[r0row * 16 + 2], sB = srcL[r1row * 16 + 2];

    int pc = 0, pg = 2;  // buffer index of P(t) and of gather target (t+2)
#pragma unroll 1
    for (int t = 0; t < 16; ++t) {
      short* Pc = Pb + pc * NPB * PSTR;
      short* Pg = Pb + pg * NPB * PSTR;
      const short* Hp = Hb + ((t + 1) & 1) * NPB * HSTR;  // h(t-1)
      short* Hw = Hb + (t & 1) * NPB * HSTR;              // h(t)
      pc = (pc == 2) ? 0 : pc + 1;
      pg = (pg == 2) ? 0 : pg + 1;

      STEP_BAR2();  // gather(t) landed everywhere; gather(t+1) stays in flight

      // ---- read P-frags and unpack INTO acc (MFMA C-operand) ----
      const short* pR = Pc + nn * PSTR + wave * 16 + quad * 4;
      uint2 p0 = *(const uint2*)(pR + 0 * 128);
      uint2 p1 = *(const uint2*)(pR + 1 * 128);
      uint2 p2 = *(const uint2*)(pR + 2 * 128);
      uint2 p3 = *(const uint2*)(pR + 3 * 128);
      f32x4 acc[4];
      {
        float2 u, v;
        u = unpack2v(p0.x); v = unpack2v(p0.y);
        acc[0][0] = u.x; acc[0][1] = u.y; acc[0][2] = v.x; acc[0][3] = v.y;
        u = unpack2v(p1.x); v = unpack2v(p1.y);
        acc[1][0] = u.x; acc[1][1] = u.y; acc[1][2] = v.x; acc[1][3] = v.y;
        u = unpack2v(p2.x); v = unpack2v(p2.y);
        acc[2][0] = u.x; acc[2][1] = u.y; acc[2][2] = v.x; acc[2][3] = v.y;
        u = unpack2v(p3.x); v = unpack2v(p3.y);
        acc[3][0] = u.x; acc[3][1] = u.y; acc[3][2] = v.x; acc[3][3] = v.y;
      }

      // ---- issue gather(t+2) (clamped dummy at t>=14 keeps vmcnt uniform) ----
      __builtin_amdgcn_global_load_lds(
          (const __attribute__((address_space(1))) unsigned int*)(P + (size_t)sA * 512 + lane * 8),
          (__attribute__((address_space(3))) unsigned int*)(Pg + r0row * PSTR), 16, 0, 0);
      __builtin_amdgcn_global_load_lds(
          (const __attribute__((address_space(1))) unsigned int*)(P + (size_t)sB * 512 + lane * 8),
          (__attribute__((address_space(3))) unsigned int*)(Pg + r1row * PSTR), 16, 0, 0);
      {
        int tn = (t + 3 < 16) ? t + 3 : 15;
        sA = srcL[r0row * 16 + tn];
        sB = srcL[r1row * 16 + tn];
      }

      // ---- acc += Whh_rows @ h(t-1)^T ----
      if (t) {
#pragma unroll
        for (int kt = 0; kt < 4; ++kt) {
          short8 hb = *(const short8*)(Hp + nn * HSTR + kt * 32 + quad * 8);
#pragma unroll
          for (int q = 0; q < 4; ++q)
            acc[q] = __builtin_amdgcn_mfma_f32_16x16x32_bf16(wreg[kt][q], hb, acc[q], 0, 0, 0);
        }
      }

      // ---- cell: pure register math, write h(t) ----
      float hv[4];
#pragma unroll
      for (int r = 0; r < 4; ++r)
        hv[r] = lstm_elem(acc[0][r], acc[1][r], acc[2][r], acc[3][r], c_st[r]);
      uint2 pk;
      pk.x = pack_bf2(hv[0], hv[1]);
      pk.y = pack_bf2(hv[2], hv[3]);
      *(uint2*)(Hw + nn * HSTR + wave * 16 + quad * 4) = pk;
    }

    BAR_LGKM();  // h(15) visible (buf1)

    // ---- FUSED output: out[node] = h15@Wl^T + bl + cur@Wr^T ----
    if (FO == 128 || wave < 4) {
      const short* Hf = Hb + NPB * HSTR;
      const int cbase = wave * 16;
      f32x4 accO = biasO;
#pragma unroll
      for (int kt = 0; kt < 4; ++kt) {
        short8 wlA = *(const short8*)(Wl + (size_t)(cbase + nn) * HID + kt * 32 + quad * 8);
        short8 hb = *(const short8*)(Hf + nn * HSTR + kt * 32 + quad * 8);
        accO = __builtin_amdgcn_mfma_f32_16x16x32_bf16(wlA, hb, accO, 0, 0, 0);
        short8 wrA = *(const short8*)(Wr + (size_t)(cbase + nn) * HID + kt * 32 + quad * 8);
        short8 cb;
        if (CURF32)
          cb = f32frag((const float*)cur + (size_t)(nodeBase + nn) * HID + kt * 32 + quad * 8);
        else
          cb = *(const short8*)((const short*)cur + (size_t)(nodeBase + nn) * HID + kt * 32 + quad * 8);
        accO = __builtin_amdgcn_mfma_f32_16x16x32_bf16(wrA, cb, accO, 0, 0, 0);
      }
      if (RELU) {
#pragma unroll
        for (int r = 0; r < 4; ++r) accO[r] = fmaxf(accO[r], 0.0f);
      }
      int node = nodeBase + nn;
      if (node < M) {
        if (OUTF32) {
          *(f32x4*)(outF + (size_t)node * FO + cbase + quad * 4) = accO;
        } else {
          uint2 pko;
          pko.x = pack_bf2(accO[0], accO[1]);
          pko.y = pack_bf2(accO[2], accO[3]);
          *(uint2*)(outB + (size_t)node * FO + cbase + quad * 4) = pko;
        }
      }
    }
  }
}

// ---------------- launcher ----------------
extern "C" void kernel_launch(void* const* d_in, const int* in_sizes, int n_in,
                              void* d_out, int out_size, void* d_ws, size_t ws_size,
                              hipStream_t stream) {
  const float* x = (const float*)d_in[0];
  const int* src = (const int*)d_in[1];
  const float* Wih[3] = {(const float*)d_in[2], (const float*)d_in[9], (const float*)d_in[16]};
  const float* Whh[3] = {(const float*)d_in[3], (const float*)d_in[10], (const float*)d_in[17]};
  const float* bih[3] = {(const float*)d_in[4], (const float*)d_in[11], (const float*)d_in[18]};
  const float* bhh[3] = {(const float*)d_in[5], (const float*)d_in[12], (const float*)d_in[19]};
  const float* Wl[3]  = {(const float*)d_in[6], (const float*)d_in[13], (const float*)d_in[20]};
  const float* bl[3]  = {(const float*)d_in[7], (const float*)d_in[14], (const float*)d_in[21]};
  const float* Wr[3]  = {(const float*)d_in[8], (const float*)d_in[15], (const float*)d_in[22]};

  const int M = in_sizes[0] / HID;  // 50000

  char* ws = (char*)d_ws;
  size_t off = 0;
  auto alloc = [&](size_t bytes) -> void* {
    void* p = ws + off;
    off += (bytes + 255) & ~(size_t)255;
    return p;
  };
  short* curA = (short*)alloc((size_t)M * HID * 2);
  short* curB = (short*)alloc((size_t)M * HID * 2);
  short* Pbuf = (short*)alloc((size_t)M * 512 * 2);
  short* wihB[3]; short* whhB[3]; short* wlB[3]; short* wrB[3]; float* bsum[3];
  for (int l = 0; l < 3; ++l) {
    wihB[l] = (short*)alloc(512 * HID * 2);
    whhB[l] = (short*)alloc(512 * HID * 2);
    wlB[l]  = (short*)alloc(HID * HID * 2);
    wrB[l]  = (short*)alloc(HID * HID * 2);
    bsum[l] = (float*)alloc(512 * 4);
  }

  const int nltiles = (M + NPB - 1) / NPB;  // 3125
  const int ntiles = (M + 31) / 32;         // 1563

  (void)hipFuncSetAttribute((const void*)lstm_fused_kernel<128, true, false, true>,
                            hipFuncAttributeMaxDynamicSharedMemorySize, LSTM_LDS_BYTES);
  (void)hipFuncSetAttribute((const void*)lstm_fused_kernel<128, true, false, false>,
                            hipFuncAttributeMaxDynamicSharedMemorySize, LSTM_LDS_BYTES);
  (void)hipFuncSetAttribute((const void*)lstm_fused_kernel<64, false, true, false>,
                            hipFuncAttributeMaxDynamicSharedMemorySize, LSTM_LDS_BYTES);

  for (int l = 0; l < 3; ++l) {
    const int Fo = (l == 2) ? 64 : 128;
    conv_layer_kernel<<<256, 256, 0, stream>>>(Wih[l], Whh[l], bih[l], bhh[l], Wl[l], Wr[l],
                                               Fo * HID, wihB[l], whhB[l], wlB[l], wrB[l], bsum[l]);
  }

  // layer 1: read x (f32) directly in both pgemm and the fused epilogue
  pgemm_kernel<true><<<784, 512, 0, stream>>>(x, wihB[0], bsum[0], Pbuf, M, ntiles);
  lstm_fused_kernel<128, true, false, true><<<512, 512, LSTM_LDS_BYTES, stream>>>(
      Pbuf, whhB[0], src, x, wlB[0], wrB[0], bl[0], curA, nullptr, M, nltiles);

  // layer 2: bf16 throughout
  pgemm_kernel<false><<<784, 512, 0, stream>>>(curA, wihB[1], bsum[1], Pbuf, M, ntiles);
  lstm_fused_kernel<128, true, false, false><<<512, 512, LSTM_LDS_BYTES, stream>>>(
      Pbuf, whhB[1], src, curA, wlB[1], wrB[1], bl[1], curB, nullptr, M, nltiles);

  // layer 3: f32 output
  pgemm_kernel<false><<<784, 512, 0, stream>>>(curB, wihB[2], bsum[2], Pbuf, M, ntiles);
  lstm_fused_kernel<64, false, true, false><<<512, 512, LSTM_LDS_BYTES, stream>>>(
      Pbuf, whhB[2], src, curB, wlB[2], wrB[2], bl[2], nullptr, (float*)d_out, M, nltiles);
}

// Round 15
// 763.238 us; speedup vs baseline: 1.0310x; 1.0260x over previous
//
#include <hip/hip_runtime.h>
#include <cstddef>
#include <cstdint>

typedef __attribute__((ext_vector_type(4))) float f32x4;
typedef __attribute__((ext_vector_type(8))) short short8;

#define HID 128
#define NK1 -1.4426950408889634f  // -log2(e)
#define PK2 2.8853900817779268f   // +2*log2(e)

// LDS-only barrier: no vmcnt(0) drain.
#define BAR_LGKM() __asm__ volatile("s_waitcnt lgkmcnt(0)\ns_barrier" ::: "memory")
// depth-2 prefetch fence: retire gather(t), keep gather(t+1) in flight
#define STEP_BAR2() __asm__ volatile("s_waitcnt vmcnt(2) lgkmcnt(0)\ns_barrier" ::: "memory")

__device__ __forceinline__ short f2bf(float f) {
  unsigned u = __builtin_bit_cast(unsigned, f);
  u += 0x7FFFu + ((u >> 16) & 1u);
  return (short)(u >> 16);
}
__device__ __forceinline__ unsigned pack_bf2(float a, float b) {
  unsigned ua = __builtin_bit_cast(unsigned, a) + 0x8000u;
  unsigned ub = __builtin_bit_cast(unsigned, b) + 0x8000u;
  return __builtin_amdgcn_perm(ub, ua, 0x07060302u);
}
__device__ __forceinline__ float2 unpack2v(int w) {
  float2 r;
  r.x = __builtin_bit_cast(float, (unsigned)(w << 16));
  r.y = __builtin_bit_cast(float, (unsigned)w & 0xffff0000u);
  return r;
}

// folded LSTM cell: inputs are PRE-SCALED pre-activations
// si,sf,so = -log2e*(gate), sg = 2log2e*(g). 5 exp2 + 2 rcp (algebraic min).
__device__ __forceinline__ float lstm_elem(float si, float sf, float sg, float so, float& c) {
  float Ei = __builtin_amdgcn_exp2f(si);
  float Ef = __builtin_amdgcn_exp2f(sf);
  float Tg = __builtin_amdgcn_exp2f(sg);
  float Eo = __builtin_amdgcn_exp2f(so);
  float u = 1.0f + Ei, w = 1.0f + Ef, v = Tg + 1.0f, Tm = Tg - 1.0f;
  float t0 = u * v;
  float num = __builtin_fmaf(c, t0, w * Tm);
  float cn = num * __builtin_amdgcn_rcpf(w * t0);
  c = cn;
  float Tc = __builtin_amdgcn_exp2f(PK2 * cn);
  return (Tc - 1.0f) * __builtin_amdgcn_rcpf((1.0f + Eo) * (Tc + 1.0f));
}

// ---------------- conversion kernels ----------------
__global__ void conv_x_kernel(const float* __restrict__ x, short* __restrict__ xb, int n) {
  int i = blockIdx.x * blockDim.x + threadIdx.x;
  int stride = gridDim.x * blockDim.x;
  for (; i < n; i += stride) xb[i] = f2bf(x[i]);
}

// pre-scales LSTM weights/bias by gate: i,f,o -> -log2e ; g -> +2log2e
__global__ void conv_layer_kernel(const float* __restrict__ Wih, const float* __restrict__ Whh,
                                  const float* __restrict__ bih, const float* __restrict__ bhh,
                                  const float* __restrict__ Wl, const float* __restrict__ Wr, int foK,
                                  short* __restrict__ wihB, short* __restrict__ whhB,
                                  short* __restrict__ wlB, short* __restrict__ wrB,
                                  float* __restrict__ bsum) {
  int i = blockIdx.x * blockDim.x + threadIdx.x;
  if (i < 512 * HID) {
    float sc = ((i >> 14) == 2) ? PK2 : NK1;  // gate = row>>7 = i>>14
    wihB[i] = f2bf(Wih[i] * sc);
    whhB[i] = f2bf(Whh[i] * sc);
  }
  if (i < foK) { wlB[i] = f2bf(Wl[i]); wrB[i] = f2bf(Wr[i]); }
  if (i < 512) bsum[i] = (bih[i] + bhh[i]) * (((i >> 7) == 2) ? PK2 : NK1);
}

// ------- persistent P-GEMM: P = A @ Wih^T + bias -> bf16 [M,512] -------------
#define OSTR 524
__global__ __launch_bounds__(512, 4) void pgemm_kernel(
    const short* __restrict__ A, const short* __restrict__ W,
    const float* __restrict__ bias, short* __restrict__ out, int M, int ntiles) {
  __shared__ short ldsO[32 * OSTR];  // 33.5 KB
  const int tid = threadIdx.x;
  const int wave = tid >> 6, lane = tid & 63;
  const int quad = lane >> 4, nn = lane & 15;
  const int cbase = wave * 64;

  short8 wreg[4][4];
#pragma unroll
  for (int kt = 0; kt < 4; ++kt)
#pragma unroll
    for (int nt = 0; nt < 4; ++nt)
      wreg[kt][nt] = *(const short8*)(W + (size_t)(cbase + nt * 16 + nn) * HID + kt * 32 + quad * 8);
  f32x4 bias4[4];
#pragma unroll
  for (int nt = 0; nt < 4; ++nt)
#pragma unroll
    for (int r = 0; r < 4; ++r) bias4[nt][r] = bias[cbase + nt * 16 + quad * 4 + r];

#pragma unroll 1
  for (int rt = blockIdx.x; rt < ntiles; rt += gridDim.x) {
    const int row0 = rt * 32;
    f32x4 acc[2][4];
#pragma unroll
    for (int b = 0; b < 2; ++b)
#pragma unroll
      for (int nt = 0; nt < 4; ++nt) acc[b][nt] = bias4[nt];
#pragma unroll
    for (int kt = 0; kt < 4; ++kt) {
      int r0 = row0 + nn;      if (r0 > M - 1) r0 = M - 1;
      int r1 = row0 + 16 + nn; if (r1 > M - 1) r1 = M - 1;
      short8 af0 = *(const short8*)(A + (size_t)r0 * HID + kt * 32 + quad * 8);
      short8 af1 = *(const short8*)(A + (size_t)r1 * HID + kt * 32 + quad * 8);
#pragma unroll
      for (int nt = 0; nt < 4; ++nt) {
        acc[0][nt] = __builtin_amdgcn_mfma_f32_16x16x32_bf16(wreg[kt][nt], af0, acc[0][nt], 0, 0, 0);
        acc[1][nt] = __builtin_amdgcn_mfma_f32_16x16x32_bf16(wreg[kt][nt], af1, acc[1][nt], 0, 0, 0);
      }
    }
    BAR_LGKM();  // previous iteration's ldsO reads complete
#pragma unroll
    for (int b = 0; b < 2; ++b)
#pragma unroll
      for (int nt = 0; nt < 4; ++nt) {
        uint2 pk;
        pk.x = pack_bf2(acc[b][nt][0], acc[b][nt][1]);
        pk.y = pack_bf2(acc[b][nt][2], acc[b][nt][3]);
        *(uint2*)(ldsO + (b * 16 + nn) * OSTR + cbase + nt * 16 + quad * 4) = pk;
      }
    BAR_LGKM();
#pragma unroll
    for (int idx = tid; idx < 32 * 64; idx += 512) {
      int row = idx >> 6, c8 = (idx & 63) * 8;
      if (row0 + row < M)
        *(short8*)(out + (size_t)(row0 + row) * 512 + c8) = *(const short8*)(ldsO + row * OSTR + c8);
    }
  }
}

// ------- persistent LSTM + FUSED output GEMM (r12 structure, best measured) --
#define NPB 16
#define PSTR 520
#define HSTR 152
#define LSTM_LDS_BYTES ((3 * NPB * PSTR + 2 * NPB * HSTR) * 2 + 256 * 4)  // 60672

template <int FO, bool RELU, bool OUTF32>
__global__ __launch_bounds__(512, 4) void lstm_fused_kernel(
    const short* __restrict__ P, const short* __restrict__ Whh,
    const int* __restrict__ src, const short* __restrict__ cur,
    const short* __restrict__ Wl, const short* __restrict__ Wr,
    const float* __restrict__ bl,
    short* __restrict__ outB, float* __restrict__ outF, int M, int ntiles) {
  extern __shared__ char smem[];
  short* Pb = (short*)smem;                 // [3][16][520]
  short* Hb = Pb + 3 * NPB * PSTR;          // [2][16][152]
  int* srcL = (int*)(Hb + 2 * NPB * HSTR);  // [256]

  const int tid = threadIdx.x;
  const int wave = tid >> 6, lane = tid & 63;
  const int quad = lane >> 4, nn = lane & 15;
  const int r0row = wave * 2, r1row = wave * 2 + 1;

  // Whh fragments: for each gate q, rows [q*128 + wave*16, +16)  (64 VGPRs)
  short8 wreg[4][4];  // [kt][q]
#pragma unroll
  for (int kt = 0; kt < 4; ++kt)
#pragma unroll
    for (int q = 0; q < 4; ++q)
      wreg[kt][q] = *(const short8*)(Whh + (size_t)(q * 128 + wave * 16 + nn) * HID + kt * 32 + quad * 8);

  // output bias for this wave's out-col chunk
  f32x4 biasO = {0.f, 0.f, 0.f, 0.f};
  if (FO == 128 || wave < 4) {
#pragma unroll
    for (int r = 0; r < 4; ++r) biasO[r] = bl[wave * 16 + quad * 4 + r];
  }

#pragma unroll 1
  for (int tile = blockIdx.x; tile < ntiles; tile += gridDim.x) {
    const int nodeBase = tile * NPB;
    if (tid < 256) {
      int node = nodeBase + (tid >> 4);
      srcL[tid] = (node < M) ? src[nodeBase * 16 + tid] : 0;
    }
    float c_st[4] = {0.f, 0.f, 0.f, 0.f};
    BAR_LGKM();  // srcL visible; prev tile's LDS reads done

    // prologue: gather(0) -> buf0, gather(1) -> buf1
    {
      int s0A = srcL[r0row * 16 + 0], s0B = srcL[r1row * 16 + 0];
      __builtin_amdgcn_global_load_lds(
          (const __attribute__((address_space(1))) unsigned int*)(P + (size_t)s0A * 512 + lane * 8),
          (__attribute__((address_space(3))) unsigned int*)(Pb + r0row * PSTR), 16, 0, 0);
      __builtin_amdgcn_global_load_lds(
          (const __attribute__((address_space(1))) unsigned int*)(P + (size_t)s0B * 512 + lane * 8),
          (__attribute__((address_space(3))) unsigned int*)(Pb + r1row * PSTR), 16, 0, 0);
      int s1A = srcL[r0row * 16 + 1], s1B = srcL[r1row * 16 + 1];
      __builtin_amdgcn_global_load_lds(
          (const __attribute__((address_space(1))) unsigned int*)(P + (size_t)s1A * 512 + lane * 8),
          (__attribute__((address_space(3))) unsigned int*)(Pb + NPB * PSTR + r0row * PSTR), 16, 0, 0);
      __builtin_amdgcn_global_load_lds(
          (const __attribute__((address_space(1))) unsigned int*)(P + (size_t)s1B * 512 + lane * 8),
          (__attribute__((address_space(3))) unsigned int*)(Pb + NPB * PSTR + r1row * PSTR), 16, 0, 0);
    }
    int sA = srcL[r0row * 16 + 2], sB = srcL[r1row * 16 + 2];

    int pc = 0, pg = 2;  // buffer index of P(t) and of gather target (t+2)
#pragma unroll 1
    for (int t = 0; t < 16; ++t) {
      short* Pc = Pb + pc * NPB * PSTR;
      short* Pg = Pb + pg * NPB * PSTR;
      const short* Hp = Hb + ((t + 1) & 1) * NPB * HSTR;  // h(t-1)
      short* Hw = Hb + (t & 1) * NPB * HSTR;              // h(t)
      pc = (pc == 2) ? 0 : pc + 1;
      pg = (pg == 2) ? 0 : pg + 1;

      STEP_BAR2();  // gather(t) landed everywhere; gather(t+1) stays in flight

      // ---- read P-frags and unpack INTO acc (MFMA C-operand) ----
      const short* pR = Pc + nn * PSTR + wave * 16 + quad * 4;
      uint2 p0 = *(const uint2*)(pR + 0 * 128);
      uint2 p1 = *(const uint2*)(pR + 1 * 128);
      uint2 p2 = *(const uint2*)(pR + 2 * 128);
      uint2 p3 = *(const uint2*)(pR + 3 * 128);
      f32x4 acc[4];
      {
        float2 u, v;
        u = unpack2v(p0.x); v = unpack2v(p0.y);
        acc[0][0] = u.x; acc[0][1] = u.y; acc[0][2] = v.x; acc[0][3] = v.y;
        u = unpack2v(p1.x); v = unpack2v(p1.y);
        acc[1][0] = u.x; acc[1][1] = u.y; acc[1][2] = v.x; acc[1][3] = v.y;
        u = unpack2v(p2.x); v = unpack2v(p2.y);
        acc[2][0] = u.x; acc[2][1] = u.y; acc[2][2] = v.x; acc[2][3] = v.y;
        u = unpack2v(p3.x); v = unpack2v(p3.y);
        acc[3][0] = u.x; acc[3][1] = u.y; acc[3][2] = v.x; acc[3][3] = v.y;
      }

      // ---- issue gather(t+2) (clamped dummy at t>=14 keeps vmcnt uniform) ----
      __builtin_amdgcn_global_load_lds(
          (const __attribute__((address_space(1))) unsigned int*)(P + (size_t)sA * 512 + lane * 8),
          (__attribute__((address_space(3))) unsigned int*)(Pg + r0row * PSTR), 16, 0, 0);
      __builtin_amdgcn_global_load_lds(
          (const __attribute__((address_space(1))) unsigned int*)(P + (size_t)sB * 512 + lane * 8),
          (__attribute__((address_space(3))) unsigned int*)(Pg + r1row * PSTR), 16, 0, 0);
      {
        int tn = (t + 3 < 16) ? t + 3 : 15;
        sA = srcL[r0row * 16 + tn];
        sB = srcL[r1row * 16 + tn];
      }

      // ---- acc += Whh_rows @ h(t-1)^T ----
      if (t) {
#pragma unroll
        for (int kt = 0; kt < 4; ++kt) {
          short8 hb = *(const short8*)(Hp + nn * HSTR + kt * 32 + quad * 8);
#pragma unroll
          for (int q = 0; q < 4; ++q)
            acc[q] = __builtin_amdgcn_mfma_f32_16x16x32_bf16(wreg[kt][q], hb, acc[q], 0, 0, 0);
        }
      }

      // ---- cell: pure register math, write h(t) ----
      float hv[4];
#pragma unroll
      for (int r = 0; r < 4; ++r)
        hv[r] = lstm_elem(acc[0][r], acc[1][r], acc[2][r], acc[3][r], c_st[r]);
      uint2 pk;
      pk.x = pack_bf2(hv[0], hv[1]);
      pk.y = pack_bf2(hv[2], hv[3]);
      *(uint2*)(Hw + nn * HSTR + wave * 16 + quad * 4) = pk;
    }

    BAR_LGKM();  // h(15) visible (buf1)

    // ---- FUSED output: out[node] = h15@Wl^T + bl + cur@Wr^T ----
    if (FO == 128 || wave < 4) {
      const short* Hf = Hb + NPB * HSTR;
      const int cbase = wave * 16;
      f32x4 accO = biasO;
#pragma unroll
      for (int kt = 0; kt < 4; ++kt) {
        short8 wlA = *(const short8*)(Wl + (size_t)(cbase + nn) * HID + kt * 32 + quad * 8);
        short8 hb = *(const short8*)(Hf + nn * HSTR + kt * 32 + quad * 8);
        accO = __builtin_amdgcn_mfma_f32_16x16x32_bf16(wlA, hb, accO, 0, 0, 0);
        short8 wrA = *(const short8*)(Wr + (size_t)(cbase + nn) * HID + kt * 32 + quad * 8);
        short8 cb = *(const short8*)(cur + (size_t)(nodeBase + nn) * HID + kt * 32 + quad * 8);
        accO = __builtin_amdgcn_mfma_f32_16x16x32_bf16(wrA, cb, accO, 0, 0, 0);
      }
      if (RELU) {
#pragma unroll
        for (int r = 0; r < 4; ++r) accO[r] = fmaxf(accO[r], 0.0f);
      }
      int node = nodeBase + nn;
      if (node < M) {
        if (OUTF32) {
          *(f32x4*)(outF + (size_t)node * FO + cbase + quad * 4) = accO;
        } else {
          uint2 pko;
          pko.x = pack_bf2(accO[0], accO[1]);
          pko.y = pack_bf2(accO[2], accO[3]);
          *(uint2*)(outB + (size_t)node * FO + cbase + quad * 4) = pko;
        }
      }
    }
  }
}

// ---------------- launcher ----------------
extern "C" void kernel_launch(void* const* d_in, const int* in_sizes, int n_in,
                              void* d_out, int out_size, void* d_ws, size_t ws_size,
                              hipStream_t stream) {
  const float* x = (const float*)d_in[0];
  const int* src = (const int*)d_in[1];
  const float* Wih[3] = {(const float*)d_in[2], (const float*)d_in[9], (const float*)d_in[16]};
  const float* Whh[3] = {(const float*)d_in[3], (const float*)d_in[10], (const float*)d_in[17]};
  const float* bih[3] = {(const float*)d_in[4], (const float*)d_in[11], (const float*)d_in[18]};
  const float* bhh[3] = {(const float*)d_in[5], (const float*)d_in[12], (const float*)d_in[19]};
  const float* Wl[3]  = {(const float*)d_in[6], (const float*)d_in[13], (const float*)d_in[20]};
  const float* bl[3]  = {(const float*)d_in[7], (const float*)d_in[14], (const float*)d_in[21]};
  const float* Wr[3]  = {(const float*)d_in[8], (const float*)d_in[15], (const float*)d_in[22]};

  const int M = in_sizes[0] / HID;  // 50000

  char* ws = (char*)d_ws;
  size_t off = 0;
  auto alloc = [&](size_t bytes) -> void* {
    void* p = ws + off;
    off += (bytes + 255) & ~(size_t)255;
    return p;
  };
  short* curA = (short*)alloc((size_t)M * HID * 2);
  short* curB = (short*)alloc((size_t)M * HID * 2);
  short* Pbuf = (short*)alloc((size_t)M * 512 * 2);
  short* wihB[3]; short* whhB[3]; short* wlB[3]; short* wrB[3]; float* bsum[3];
  for (int l = 0; l < 3; ++l) {
    wihB[l] = (short*)alloc(512 * HID * 2);
    whhB[l] = (short*)alloc(512 * HID * 2);
    wlB[l]  = (short*)alloc(HID * HID * 2);
    wrB[l]  = (short*)alloc(HID * HID * 2);
    bsum[l] = (float*)alloc(512 * 4);
  }

  const int nltiles = (M + NPB - 1) / NPB;  // 3125
  const int ntiles = (M + 31) / 32;         // 1563

  (void)hipFuncSetAttribute((const void*)lstm_fused_kernel<128, true, false>,
                            hipFuncAttributeMaxDynamicSharedMemorySize, LSTM_LDS_BYTES);
  (void)hipFuncSetAttribute((const void*)lstm_fused_kernel<64, false, true>,
                            hipFuncAttributeMaxDynamicSharedMemorySize, LSTM_LDS_BYTES);

  conv_x_kernel<<<2048, 256, 0, stream>>>(x, curA, M * HID);
  for (int l = 0; l < 3; ++l) {
    const int Fo = (l == 2) ? 64 : 128;
    conv_layer_kernel<<<256, 256, 0, stream>>>(Wih[l], Whh[l], bih[l], bhh[l], Wl[l], Wr[l],
                                               Fo * HID, wihB[l], whhB[l], wlB[l], wrB[l], bsum[l]);
  }

  short* cur = curA;
  short* nxt = curB;
  for (int l = 0; l < 3; ++l) {
    pgemm_kernel<<<784, 512, 0, stream>>>(cur, wihB[l], bsum[l], Pbuf, M, ntiles);
    if (l < 2) {
      lstm_fused_kernel<128, true, false><<<512, 512, LSTM_LDS_BYTES, stream>>>(
          Pbuf, whhB[l], src, cur, wlB[l], wrB[l], bl[l], nxt, nullptr, M, nltiles);
      short* tswap = cur; cur = nxt; nxt = tswap;
    } else {
      lstm_fused_kernel<64, false, true><<<512, 512, LSTM_LDS_BYTES, stream>>>(
          Pbuf, whhB[l], src, cur, wlB[l], wrB[l], bl[l], nullptr, (float*)d_out, M, nltiles);
    }
  }
}